// Round 2
// baseline (545.355 us; speedup 1.0000x reference)
//
#include <hip/hip_runtime.h>

// LinearAttention forward on gfx950.
// R2: k-major LDS chunk layout in MFMA kernels (kills 4-way read bank conflicts
// at zero instruction cost by permuting global_load_lds source addresses),
// sS padded to stride 136 (kills 16-way conflict), split-K gate GEMM1,
// merged transpose launches (19 -> 13 dispatches).

#define DEV __device__ __forceinline__
typedef unsigned short u16;
typedef __bf16 bf16x8 __attribute__((ext_vector_type(8)));
typedef float f32x4 __attribute__((ext_vector_type(4)));
typedef u16 u16x8 __attribute__((ext_vector_type(8)));

DEV u16 f2bf(float f) {
  unsigned u = __builtin_bit_cast(unsigned, f);
  u += 0x7fffu + ((u >> 16) & 1u);
  return (u16)(u >> 16);
}
DEV float bf2f(u16 h) {
  unsigned u = ((unsigned)h) << 16;
  return __builtin_bit_cast(float, u);
}
DEV void async16(const u16* g, u16* l) {
  __builtin_amdgcn_global_load_lds(
      (const __attribute__((address_space(1))) unsigned int*)g,
      (__attribute__((address_space(3))) unsigned int*)l, 16, 0, 0);
}

// ---------------- elementwise converts ----------------
__global__ void convert_f32_bf16(const float* __restrict__ in, u16* __restrict__ out, long n) {
  long i = ((long)blockIdx.x * blockDim.x + threadIdx.x) * 4;
  if (i >= n) return;
  float4 v = *(const float4*)(in + i);
  ushort4 p;
  p.x = f2bf(v.x); p.y = f2bf(v.y); p.z = f2bf(v.z); p.w = f2bf(v.w);
  *(ushort4*)(out + i) = p;
}

// all weight transposes in one launch. fp32 [K][N] -> bf16 [N][K]
__global__ void transpose_all(const float* __restrict__ Wq, const float* __restrict__ Wk,
                              const float* __restrict__ Wv, const float* __restrict__ Wo,
                              const float* __restrict__ Wg1, const float* __restrict__ Wg2,
                              u16* __restrict__ wtqkv, u16* __restrict__ wot,
                              u16* __restrict__ wg1t, u16* __restrict__ wg2t) {
  __shared__ float t[32][33];
  int id = blockIdx.x;
  const float* in; u16* out; int K, N, bx, by;
  if (id < 12288) {
    int w = id >> 12, tt = id & 4095;
    in = (w == 0) ? Wq : (w == 1) ? Wk : Wv;
    out = wtqkv + (long)w * 2048 * 2048;
    K = 2048; N = 2048; bx = tt & 63; by = tt >> 6;
  } else if (id < 16384) {
    int tt = id - 12288;
    in = Wo; out = wot; K = 2048; N = 2048; bx = tt & 63; by = tt >> 6;
  } else if (id < 16640) {
    int tt = id - 16384;
    in = Wg1; out = wg1t; K = 2048; N = 128; bx = tt & 3; by = tt >> 2;
  } else {
    int tt = id - 16640;
    in = Wg2; out = wg2t; K = 128; N = 2048; bx = tt & 63; by = tt >> 6;
  }
  int c = threadIdx.x & 31, r0 = threadIdx.x >> 5;
  for (int r = r0; r < 32; r += 8)
    t[r][c] = in[(long)(by * 32 + r) * N + bx * 32 + c];
  __syncthreads();
  for (int r = r0; r < 32; r += 8)
    out[(long)(bx * 32 + r) * K + by * 32 + c] = f2bf(t[c][r]);
}

// ---------------- GEMM: C[M][N] = A[M][K] @ B^T, B stored [N][K], bf16 in ----------------
// LDS chunk layout is k-major: within a 16-row x 32-k chunk, lane l stages
// global (row = l&15, kquad = l>>4) so fragment reads hit bank base fm*4%32
// (<=2-way, free) instead of (fm&1)*16 (4-way).
template <typename OutT>
__global__ __launch_bounds__(256, 2) void gemm_bt(
    const u16* __restrict__ A, const u16* __restrict__ B, OutT* __restrict__ C,
    int M, int N, int K, int lda, int ldb, int ldc,
    int nc, long sA1, long sA2, long sB1, long sB2, long sC1, long sC2) {
  __shared__ u16 sA[128 * 32], sB[128 * 32];
  {
    int z = blockIdx.z, z1 = z / nc, z2 = z % nc;
    A += z1 * sA1 + z2 * sA2;
    B += z1 * sB1 + z2 * sB2;
    C += z1 * sC1 + z2 * sC2;
  }
  const int tid = threadIdx.x, lane = tid & 63, wid = tid >> 6;
  const int bm = blockIdx.y * 128, bn = blockIdx.x * 128;
  const int ch0 = wid * 2, ch1 = ch0 + 1;
  const int rr = lane & 15, kq = lane >> 4, ak = kq * 8;
  const int ar0 = ch0 * 16 + rr, ar1 = ch1 * 16 + rr;
  const u16* gA0 = A + (long)(bm + ar0) * lda + ak;
  const u16* gA1 = A + (long)(bm + ar1) * lda + ak;
  const u16* gB0 = B + (long)(bn + ar0) * ldb + ak;
  const u16* gB1 = B + (long)(bn + ar1) * ldb + ak;
  u16* lA0 = sA + ch0 * 512; u16* lA1 = sA + ch1 * 512;
  u16* lB0 = sB + ch0 * 512; u16* lB1 = sB + ch1 * 512;
  const int wm = (wid & 1) * 64, wn = (wid >> 1) * 64;
  const int fm = lane & 15;
  const int aoff = (wm >> 4) * 512 + kq * 128 + fm * 8;
  const int boff = (wn >> 4) * 512 + kq * 128 + fm * 8;
  f32x4 acc[4][4] = {};
  for (int kb = 0; kb < K; kb += 32) {
    async16(gA0, lA0); async16(gA1, lA1);
    async16(gB0, lB0); async16(gB1, lB1);
    gA0 += 32; gA1 += 32; gB0 += 32; gB1 += 32;
    __syncthreads();
    bf16x8 af[4], bfr[4];
#pragma unroll
    for (int i = 0; i < 4; i++) af[i] = *(const bf16x8*)&sA[aoff + i * 512];
#pragma unroll
    for (int i = 0; i < 4; i++) bfr[i] = *(const bf16x8*)&sB[boff + i * 512];
#pragma unroll
    for (int mt = 0; mt < 4; mt++)
#pragma unroll
      for (int nt = 0; nt < 4; nt++)
        acc[mt][nt] = __builtin_amdgcn_mfma_f32_16x16x32_bf16(af[mt], bfr[nt], acc[mt][nt], 0, 0, 0);
    __syncthreads();
  }
  const int cr = (lane >> 4) * 4;
#pragma unroll
  for (int mt = 0; mt < 4; mt++)
#pragma unroll
    for (int nt = 0; nt < 4; nt++)
#pragma unroll
      for (int r = 0; r < 4; r++) {
        long row = bm + wm + mt * 16 + cr + r;
        long col = bn + wn + nt * 16 + fm;
        float v = acc[mt][nt][r];
        if constexpr (sizeof(OutT) == 2) C[row * ldc + col] = f2bf(v);
        else                             C[row * ldc + col] = v;
      }
}

// ---------------- reduce split-K partials -> bf16 ----------------
__global__ void reduce_g1(const float* __restrict__ p, u16* __restrict__ g1) {
  long i = ((long)blockIdx.x * 256 + threadIdx.x) * 4;
  float4 s = *(const float4*)(p + i);
#pragma unroll
  for (int z = 1; z < 8; z++) {
    float4 a = *(const float4*)(p + z * 524288L + i);
    s.x += a.x; s.y += a.y; s.z += a.z; s.w += a.w;
  }
  ushort4 o;
  o.x = f2bf(s.x); o.y = f2bf(s.y); o.z = f2bf(s.z); o.w = f2bf(s.w);
  *(ushort4*)(g1 + i) = o;
}

// ---------------- silu + LRPE rotate (in-place on q,k slabs of qkv) ----------------
__global__ void silu_rotate(u16* __restrict__ qkv) {
  int idx = blockIdx.x * 256 + threadIdx.x; // [b:1][t:11][h:4][j:6]
  int j = idx & 63, h = (idx >> 6) & 15, t = (idx >> 10) & 2047, b = idx >> 21;
  u16* q = qkv + (long)(b * 2048 + t) * 6144 + h * 128;
  u16* k = q + 2048;
  float theta = exp2f(-13.287712379549449f * (float)j * (1.0f / 64.0f)); // 10000^(-j/64)
  float ang = (float)t * theta;
  float sn, cs;
  sincosf(ang, &sn, &cs);
  float q1 = bf2f(q[j]), q2 = bf2f(q[j + 64]);
  q1 = q1 / (1.f + expf(-q1)); q2 = q2 / (1.f + expf(-q2));
  q[j] = f2bf(q1 * cs - q2 * sn); q[j + 64] = f2bf(q1 * sn + q2 * cs);
  float k1 = bf2f(k[j]), k2 = bf2f(k[j + 64]);
  k1 = k1 / (1.f + expf(-k1)); k2 = k2 / (1.f + expf(-k2));
  k[j] = f2bf(k1 * cs - k2 * sn); k[j + 64] = f2bf(k1 * sn + k2 * cs);
}

// ---------------- per-(b,h) head transpose: [n][dd] -> [dd][n], k gets decay fold ----------------
__global__ void transpose_kv(const u16* __restrict__ qkv, u16* __restrict__ kdT,
                             u16* __restrict__ vT) {
  __shared__ float t[32][33];
  int z = blockIdx.z, which = z >> 5, bh = z & 31;
  int b = bh >> 4, h = bh & 15;
  u16* out = which ? vT : kdT;
  int slab = which ? 2 : 1, decay = which ? 0 : 1;
  int n0 = blockIdx.x * 32, d0 = blockIdx.y * 32;
  int cc = threadIdx.x & 31, rr0 = threadIdx.x >> 5;
  float log_lam = -exp2f(-0.5f * (float)(h + 1));
  for (int rr = rr0; rr < 32; rr += 8) {
    int n = n0 + rr;
    float v = bf2f(qkv[(long)(b * 2048 + n) * 6144 + slab * 2048 + h * 128 + d0 + cc]);
    if (decay) v *= expf(log_lam * (float)(127 - (n & 127)));
    t[rr][cc] = v;
  }
  __syncthreads();
  for (int rr = rr0; rr < 32; rr += 8)
    out[((long)bh * 128 + d0 + rr) * 2048 + n0 + cc] = f2bf(t[cc][rr]);
}

// ---------------- decay scan over chunks: S_c = lamC*S_{c-1} + U_{c-1}, S_0 = 0 ----------------
__global__ void scan_state(const u16* __restrict__ U, u16* __restrict__ S_all) {
  int blk = blockIdx.x; // 256 blocks: [bh:32][slice:8]
  int bh = blk >> 3, sl = blk & 7, h = bh & 15;
  float log_lam = -exp2f(-0.5f * (float)(h + 1));
  float lamC = expf(log_lam * 128.f);
  long off = (long)bh * 16 * 16384 + sl * 2048 + threadIdx.x * 8;
  float s[8];
#pragma unroll
  for (int j = 0; j < 8; j++) s[j] = 0.f;
  for (int c = 0; c < 16; c++) {
    long idx = off + (long)c * 16384;
    u16x8 sb;
#pragma unroll
    for (int j = 0; j < 8; j++) sb[j] = f2bf(s[j]);
    *(u16x8*)(S_all + idx) = sb;
    u16x8 ub = *(const u16x8*)(U + idx);
#pragma unroll
    for (int j = 0; j < 8; j++) s[j] = lamC * s[j] + bf2f(ub[j]);
  }
}

// ---------------- fused per-(b,h,c) attention output ----------------
__global__ __launch_bounds__(256, 1) void attn_out(
    const u16* __restrict__ qkv, const u16* __restrict__ vT,
    const u16* __restrict__ S_all, float* __restrict__ o) {
  __shared__ u16 sA[128 * 32], sB[128 * 32], sK[128 * 32];
  __shared__ u16 sS[128 * 136]; // stride 136: breaks 16-way bank conflict
  const int blk = blockIdx.x;
  const int bh = blk >> 4, c = blk & 15;
  const int b = bh >> 4, h = bh & 15;
  const float log_lam = -exp2f(-0.5f * (float)(h + 1));
  const int tid = threadIdx.x, lane = tid & 63, wid = tid >> 6;
  const int wm = (wid & 1) * 64, wn = (wid >> 1) * 64;
  const int fm = lane & 15, fq = lane >> 4;
  const int ch0 = wid * 2, ch1 = ch0 + 1;
  const int rr = lane & 15, kq = lane >> 4, ak = kq * 8, fk = kq * 8;
  const int r0 = ch0 * 16 + rr, r1 = ch1 * 16 + rr;
  const int aoff = (wm >> 4) * 512 + kq * 128 + fm * 8;
  const int boff = (wn >> 4) * 512 + kq * 128 + fm * 8;
  const u16* qbase = qkv + (long)(b * 2048 + c * 128) * 6144 + h * 128; // rows t, stride 6144
  const u16* kbase = qbase + 2048;                                     // rows s
  const u16* Sbase = S_all + ((long)bh * 16 + c) * 16384;              // [e][d], stride 128
  const u16* vbase = vT + (long)bh * 262144 + (long)c * 128;           // rows e, stride 2048

  f32x4 acc[4][4] = {}; // o_inter, then O total
  f32x4 sc[4][4] = {};  // scores
  // Phase 1+2: o_inter = Q @ S_c   and   scores = Q @ K^T (shared Q staging)
  for (int kb = 0; kb < 128; kb += 32) {
    async16(qbase + (long)r0 * 6144 + kb + ak, sA + ch0 * 512);
    async16(qbase + (long)r1 * 6144 + kb + ak, sA + ch1 * 512);
    async16(Sbase + r0 * 128 + kb + ak, sB + ch0 * 512);
    async16(Sbase + r1 * 128 + kb + ak, sB + ch1 * 512);
    async16(kbase + (long)r0 * 6144 + kb + ak, sK + ch0 * 512);
    async16(kbase + (long)r1 * 6144 + kb + ak, sK + ch1 * 512);
    __syncthreads();
    bf16x8 aq[4], bs[4], bk[4];
#pragma unroll
    for (int i = 0; i < 4; i++) {
      aq[i] = *(const bf16x8*)&sA[aoff + i * 512];
      bs[i] = *(const bf16x8*)&sB[boff + i * 512];
      bk[i] = *(const bf16x8*)&sK[boff + i * 512];
    }
#pragma unroll
    for (int mt = 0; mt < 4; mt++)
#pragma unroll
      for (int nt = 0; nt < 4; nt++) {
        acc[mt][nt] = __builtin_amdgcn_mfma_f32_16x16x32_bf16(aq[mt], bs[nt], acc[mt][nt], 0, 0, 0);
        sc[mt][nt] = __builtin_amdgcn_mfma_f32_16x16x32_bf16(aq[mt], bk[nt], sc[mt][nt], 0, 0, 0);
      }
    __syncthreads();
  }
  // scale o_inter rows by decay_q(t) = exp(log_lam*(t+1))
#pragma unroll
  for (int mt = 0; mt < 4; mt++)
#pragma unroll
    for (int r = 0; r < 4; r++) {
      int t = wm + mt * 16 + fq * 4 + r;
      float d = expf(log_lam * (float)(t + 1));
#pragma unroll
      for (int nt = 0; nt < 4; nt++) acc[mt][nt][r] *= d;
    }
  // mask+decay scores, write bf16 to sS[t][s]
#pragma unroll
  for (int mt = 0; mt < 4; mt++)
#pragma unroll
    for (int nt = 0; nt < 4; nt++)
#pragma unroll
      for (int r = 0; r < 4; r++) {
        int t = wm + mt * 16 + fq * 4 + r;
        int s = wn + nt * 16 + fm;
        float v = sc[mt][nt][r];
        v = (t >= s) ? v * expf(log_lam * (float)(t - s)) : 0.f;
        sS[t * 136 + s] = f2bf(v);
      }
  __syncthreads();
  // Phase 3: O += scores @ V   (A from sS, B staged from vT)
  for (int kb = 0; kb < 128; kb += 32) {
    async16(vbase + r0 * 2048 + kb + ak, sB + ch0 * 512);
    async16(vbase + r1 * 2048 + kb + ak, sB + ch1 * 512);
    __syncthreads();
    bf16x8 as[4], bv[4];
#pragma unroll
    for (int i = 0; i < 4; i++) {
      as[i] = *(const bf16x8*)&sS[(wm + i * 16 + fm) * 136 + kb + fk];
      bv[i] = *(const bf16x8*)&sB[boff + i * 512];
    }
#pragma unroll
    for (int mt = 0; mt < 4; mt++)
#pragma unroll
      for (int nt = 0; nt < 4; nt++)
        acc[mt][nt] = __builtin_amdgcn_mfma_f32_16x16x32_bf16(as[mt], bv[nt], acc[mt][nt], 0, 0, 0);
    __syncthreads();
  }
  // write O fp32 [b*2048+c*128+t][h*128+e]
  long orow0 = (long)(b * 2048 + c * 128);
#pragma unroll
  for (int mt = 0; mt < 4; mt++)
#pragma unroll
    for (int nt = 0; nt < 4; nt++)
#pragma unroll
      for (int r = 0; r < 4; r++) {
        int t = wm + mt * 16 + fq * 4 + r;
        int e = wn + nt * 16 + fm;
        o[(orow0 + t) * 2048 + h * 128 + e] = acc[mt][nt][r];
      }
}

// ---------------- gated per-head RMSNorm -> bf16 ----------------
__global__ void gated_norm(const float* __restrict__ o, const u16* __restrict__ gate,
                           const float* __restrict__ w, u16* __restrict__ out) {
  int gidx = blockIdx.x * 4 + (threadIdx.x >> 6); // token*16 + h
  int lane = threadIdx.x & 63;
  int h = gidx & 15;
  long base = (long)(gidx >> 4) * 2048 + h * 128;
  float x0 = o[base + lane], x1 = o[base + 64 + lane];
  float g0 = bf2f(gate[base + lane]), g1 = bf2f(gate[base + 64 + lane]);
  x0 *= 1.f / (1.f + expf(-g0));
  x1 *= 1.f / (1.f + expf(-g1));
  float ss = x0 * x0 + x1 * x1;
#pragma unroll
  for (int off = 32; off; off >>= 1) ss += __shfl_xor(ss, off);
  float r = rsqrtf(ss * (1.f / 128.f) + 1e-6f);
  out[base + lane] = f2bf(x0 * r * w[h * 128 + lane]);
  out[base + 64 + lane] = f2bf(x1 * r * w[h * 128 + 64 + lane]);
}

// ---------------- host ----------------
extern "C" void kernel_launch(void* const* d_in, const int* in_sizes, int n_in,
                              void* d_out, int out_size, void* d_ws, size_t ws_size,
                              hipStream_t stream) {
  (void)in_sizes; (void)n_in; (void)out_size; (void)ws_size;
  const float* x   = (const float*)d_in[0];
  const float* Wq  = (const float*)d_in[1];
  const float* Wk  = (const float*)d_in[2];
  const float* Wv  = (const float*)d_in[3];
  const float* Wo  = (const float*)d_in[4];
  const float* Wg1 = (const float*)d_in[5];
  const float* Wg2 = (const float*)d_in[6];
  const float* nw  = (const float*)d_in[7];
  float* out = (float*)d_out;

  char* ws = (char*)d_ws;
  size_t off = 0;
  auto alloc = [&](size_t bytes) -> void* {
    void* p = ws + off;
    off += (bytes + 255) & ~(size_t)255;
    return p;
  };
  u16* xb    = (u16*)alloc(4096UL * 2048 * 2);
  u16* wtqkv = (u16*)alloc(6144UL * 2048 * 2);
  u16* wot   = (u16*)alloc(2048UL * 2048 * 2);
  u16* wg1t  = (u16*)alloc(128UL * 2048 * 2);
  u16* wg2t  = (u16*)alloc(2048UL * 128 * 2);
  u16* qkv   = (u16*)alloc(4096UL * 6144 * 2);
  u16* g1    = (u16*)alloc(4096UL * 128 * 2);
  u16* gate  = (u16*)alloc(4096UL * 2048 * 2); // also aliased as fp32 split-K partials
  u16* kdT   = (u16*)alloc(32UL * 128 * 2048 * 2);
  u16* vT    = (u16*)alloc(32UL * 128 * 2048 * 2);
  u16* Ubuf  = (u16*)alloc(512UL * 16384 * 2);
  u16* S_all = (u16*)alloc(512UL * 16384 * 2);
  float* ob  = (float*)alloc(4096UL * 2048 * 4);
  u16* nrm   = (u16*)alloc(4096UL * 2048 * 2);
  float* g1p = (float*)gate; // 8 x 4096 x 128 fp32 = 16.8 MB, exactly gate's size

  // 1. bf16 conversions / weight transposes
  convert_f32_bf16<<<dim3(8192), dim3(256), 0, stream>>>(x, xb, 8388608L);
  transpose_all<<<dim3(16896), dim3(256), 0, stream>>>(Wq, Wk, Wv, Wo, Wg1, Wg2,
                                                       wtqkv, wot, wg1t, wg2t);
  // 2. projections
  gemm_bt<u16><<<dim3(48, 32, 1), dim3(256), 0, stream>>>(xb, wtqkv, qkv,
      4096, 6144, 2048, 2048, 2048, 6144, 1, 0, 0, 0, 0, 0, 0);
  // gate GEMM1 with split-K=8 (grid 256 blocks instead of 32)
  gemm_bt<float><<<dim3(1, 32, 8), dim3(256), 0, stream>>>(xb, wg1t, g1p,
      4096, 128, 256, 2048, 2048, 128, 1, 256L, 0, 256L, 0, 524288L, 0);
  silu_rotate<<<dim3(16384), dim3(256), 0, stream>>>(qkv);
  reduce_g1<<<dim3(512), dim3(256), 0, stream>>>(g1p, g1);
  gemm_bt<u16><<<dim3(16, 32, 1), dim3(256), 0, stream>>>(g1, wg2t, gate,
      4096, 2048, 128, 128, 128, 2048, 1, 0, 0, 0, 0, 0, 0);
  // 3. attention
  transpose_kv<<<dim3(64, 4, 64), dim3(256), 0, stream>>>(qkv, kdT, vT);
  gemm_bt<u16><<<dim3(1, 1, 512), dim3(256), 0, stream>>>(vT, kdT, Ubuf,
      128, 128, 128, 2048, 2048, 128,
      16, 262144L, 128L, 262144L, 128L, 262144L, 16384L);
  scan_state<<<dim3(256), dim3(256), 0, stream>>>(Ubuf, S_all);
  attn_out<<<dim3(512), dim3(256), 0, stream>>>(qkv, vT, S_all, ob);
  // 4. gated group-RMSNorm + output projection
  gated_norm<<<dim3(16384), dim3(256), 0, stream>>>(ob, gate, nw, nrm);
  gemm_bt<float><<<dim3(16, 32, 1), dim3(256), 0, stream>>>(nrm, wot, out,
      4096, 2048, 2048, 2048, 2048, 2048, 1, 0, 0, 0, 0, 0, 0);
}

// Round 3
// 449.316 us; speedup vs baseline: 1.2137x; 1.2137x over previous
//
#include <hip/hip_runtime.h>

// LinearAttention forward on gfx950.
// R3: staging keeps R1's quad-coalesced global pattern (each 4-lane quad = one
// contiguous 64B row segment) but rotates the 16B piece assignment within each
// quad by rho(row)=(row>>1)&3. Fragment reads then hit all 8 four-bank groups
// (2-way aliasing = free) instead of 2 groups (8-way). Zero extra instructions
// in the K-loop. sS padded to 136. Split-K gate GEMM1, merged transposes.

#define DEV __device__ __forceinline__
typedef unsigned short u16;
typedef __bf16 bf16x8 __attribute__((ext_vector_type(8)));
typedef float f32x4 __attribute__((ext_vector_type(4)));
typedef u16 u16x8 __attribute__((ext_vector_type(8)));

DEV u16 f2bf(float f) {
  unsigned u = __builtin_bit_cast(unsigned, f);
  u += 0x7fffu + ((u >> 16) & 1u);
  return (u16)(u >> 16);
}
DEV float bf2f(u16 h) {
  unsigned u = ((unsigned)h) << 16;
  return __builtin_bit_cast(float, u);
}
DEV void async16(const u16* g, u16* l) {
  __builtin_amdgcn_global_load_lds(
      (const __attribute__((address_space(1))) unsigned int*)g,
      (__attribute__((address_space(3))) unsigned int*)l, 16, 0, 0);
}

// ---------------- elementwise converts ----------------
__global__ void convert_f32_bf16(const float* __restrict__ in, u16* __restrict__ out, long n) {
  long i = ((long)blockIdx.x * blockDim.x + threadIdx.x) * 4;
  if (i >= n) return;
  float4 v = *(const float4*)(in + i);
  ushort4 p;
  p.x = f2bf(v.x); p.y = f2bf(v.y); p.z = f2bf(v.z); p.w = f2bf(v.w);
  *(ushort4*)(out + i) = p;
}

// all weight transposes in one launch. fp32 [K][N] -> bf16 [N][K]
__global__ void transpose_all(const float* __restrict__ Wq, const float* __restrict__ Wk,
                              const float* __restrict__ Wv, const float* __restrict__ Wo,
                              const float* __restrict__ Wg1, const float* __restrict__ Wg2,
                              u16* __restrict__ wtqkv, u16* __restrict__ wot,
                              u16* __restrict__ wg1t, u16* __restrict__ wg2t) {
  __shared__ float t[32][33];
  int id = blockIdx.x;
  const float* in; u16* out; int K, N, bx, by;
  if (id < 12288) {
    int w = id >> 12, tt = id & 4095;
    in = (w == 0) ? Wq : (w == 1) ? Wk : Wv;
    out = wtqkv + (long)w * 2048 * 2048;
    K = 2048; N = 2048; bx = tt & 63; by = tt >> 6;
  } else if (id < 16384) {
    int tt = id - 12288;
    in = Wo; out = wot; K = 2048; N = 2048; bx = tt & 63; by = tt >> 6;
  } else if (id < 16640) {
    int tt = id - 16384;
    in = Wg1; out = wg1t; K = 2048; N = 128; bx = tt & 3; by = tt >> 2;
  } else {
    int tt = id - 16640;
    in = Wg2; out = wg2t; K = 128; N = 2048; bx = tt & 63; by = tt >> 6;
  }
  int c = threadIdx.x & 31, r0 = threadIdx.x >> 5;
  for (int r = r0; r < 32; r += 8)
    t[r][c] = in[(long)(by * 32 + r) * N + bx * 32 + c];
  __syncthreads();
  for (int r = r0; r < 32; r += 8)
    out[(long)(bx * 32 + r) * K + by * 32 + c] = f2bf(t[c][r]);
}

// ---------------- GEMM: C[M][N] = A[M][K] @ B^T, B stored [N][K], bf16 in ----------------
// Staging: lane 4r+i fetches row r, 16B piece q=(i-(r>>1))&3 (quad covers one
// contiguous 64B segment -> coalesced). Fragment read for (row fm, kquad kq)
// is at piece ((kq+(fm>>1))&3) -> 2-way max bank aliasing (free).
template <typename OutT>
__global__ __launch_bounds__(256, 2) void gemm_bt(
    const u16* __restrict__ A, const u16* __restrict__ B, OutT* __restrict__ C,
    int M, int N, int K, int lda, int ldb, int ldc,
    int nc, long sA1, long sA2, long sB1, long sB2, long sC1, long sC2) {
  __shared__ u16 sA[128 * 32], sB[128 * 32];
  {
    int z = blockIdx.z, z1 = z / nc, z2 = z % nc;
    A += z1 * sA1 + z2 * sA2;
    B += z1 * sB1 + z2 * sB2;
    C += z1 * sC1 + z2 * sC2;
  }
  const int tid = threadIdx.x, lane = tid & 63, wid = tid >> 6;
  const int bm = blockIdx.y * 128, bn = blockIdx.x * 128;
  const int ch0 = wid * 2, ch1 = ch0 + 1;
  const int lr = lane >> 2;                                  // local row 0..15
  const int ak = (((lane & 3) - ((lane >> 3) & 3)) & 3) * 8; // rotated k-piece
  const int ar0 = ch0 * 16 + lr, ar1 = ch1 * 16 + lr;
  const u16* gA0 = A + (long)(bm + ar0) * lda + ak;
  const u16* gA1 = A + (long)(bm + ar1) * lda + ak;
  const u16* gB0 = B + (long)(bn + ar0) * ldb + ak;
  const u16* gB1 = B + (long)(bn + ar1) * ldb + ak;
  u16* lA0 = sA + ch0 * 512; u16* lA1 = sA + ch1 * 512;
  u16* lB0 = sB + ch0 * 512; u16* lB1 = sB + ch1 * 512;
  const int wm = (wid & 1) * 64, wn = (wid >> 1) * 64;
  const int fm = lane & 15, kq = lane >> 4;
  const int qs = ((kq + (fm >> 1)) & 3) * 8;
  const int aoff = (wm >> 4) * 512 + fm * 32 + qs;
  const int boff = (wn >> 4) * 512 + fm * 32 + qs;
  f32x4 acc[4][4] = {};
  for (int kb = 0; kb < K; kb += 32) {
    async16(gA0, lA0); async16(gA1, lA1);
    async16(gB0, lB0); async16(gB1, lB1);
    gA0 += 32; gA1 += 32; gB0 += 32; gB1 += 32;
    __syncthreads();
    bf16x8 af[4], bfr[4];
#pragma unroll
    for (int i = 0; i < 4; i++) af[i] = *(const bf16x8*)&sA[aoff + i * 512];
#pragma unroll
    for (int i = 0; i < 4; i++) bfr[i] = *(const bf16x8*)&sB[boff + i * 512];
#pragma unroll
    for (int mt = 0; mt < 4; mt++)
#pragma unroll
      for (int nt = 0; nt < 4; nt++)
        acc[mt][nt] = __builtin_amdgcn_mfma_f32_16x16x32_bf16(af[mt], bfr[nt], acc[mt][nt], 0, 0, 0);
    __syncthreads();
  }
  const int cr = (lane >> 4) * 4;
#pragma unroll
  for (int mt = 0; mt < 4; mt++)
#pragma unroll
    for (int nt = 0; nt < 4; nt++)
#pragma unroll
      for (int r = 0; r < 4; r++) {
        long row = bm + wm + mt * 16 + cr + r;
        long col = bn + wn + nt * 16 + fm;
        float v = acc[mt][nt][r];
        if constexpr (sizeof(OutT) == 2) C[row * ldc + col] = f2bf(v);
        else                             C[row * ldc + col] = v;
      }
}

// ---------------- reduce split-K partials -> bf16 ----------------
__global__ void reduce_g1(const float* __restrict__ p, u16* __restrict__ g1) {
  long i = ((long)blockIdx.x * 256 + threadIdx.x) * 4;
  float4 s = *(const float4*)(p + i);
#pragma unroll
  for (int z = 1; z < 8; z++) {
    float4 a = *(const float4*)(p + z * 524288L + i);
    s.x += a.x; s.y += a.y; s.z += a.z; s.w += a.w;
  }
  ushort4 o;
  o.x = f2bf(s.x); o.y = f2bf(s.y); o.z = f2bf(s.z); o.w = f2bf(s.w);
  *(ushort4*)(g1 + i) = o;
}

// ---------------- silu + LRPE rotate (in-place on q,k slabs of qkv) ----------------
__global__ void silu_rotate(u16* __restrict__ qkv) {
  int idx = blockIdx.x * 256 + threadIdx.x; // [b:1][t:11][h:4][j:6]
  int j = idx & 63, h = (idx >> 6) & 15, t = (idx >> 10) & 2047, b = idx >> 21;
  u16* q = qkv + (long)(b * 2048 + t) * 6144 + h * 128;
  u16* k = q + 2048;
  float theta = exp2f(-13.287712379549449f * (float)j * (1.0f / 64.0f)); // 10000^(-j/64)
  float ang = (float)t * theta;
  float sn, cs;
  sincosf(ang, &sn, &cs);
  float q1 = bf2f(q[j]), q2 = bf2f(q[j + 64]);
  q1 = q1 / (1.f + expf(-q1)); q2 = q2 / (1.f + expf(-q2));
  q[j] = f2bf(q1 * cs - q2 * sn); q[j + 64] = f2bf(q1 * sn + q2 * cs);
  float k1 = bf2f(k[j]), k2 = bf2f(k[j + 64]);
  k1 = k1 / (1.f + expf(-k1)); k2 = k2 / (1.f + expf(-k2));
  k[j] = f2bf(k1 * cs - k2 * sn); k[j + 64] = f2bf(k1 * sn + k2 * cs);
}

// ---------------- per-(b,h) head transpose: [n][dd] -> [dd][n], k gets decay fold ----------------
__global__ void transpose_kv(const u16* __restrict__ qkv, u16* __restrict__ kdT,
                             u16* __restrict__ vT) {
  __shared__ float t[32][33];
  int z = blockIdx.z, which = z >> 5, bh = z & 31;
  int b = bh >> 4, h = bh & 15;
  u16* out = which ? vT : kdT;
  int slab = which ? 2 : 1, decay = which ? 0 : 1;
  int n0 = blockIdx.x * 32, d0 = blockIdx.y * 32;
  int cc = threadIdx.x & 31, rr0 = threadIdx.x >> 5;
  float log_lam = -exp2f(-0.5f * (float)(h + 1));
  for (int rr = rr0; rr < 32; rr += 8) {
    int n = n0 + rr;
    float v = bf2f(qkv[(long)(b * 2048 + n) * 6144 + slab * 2048 + h * 128 + d0 + cc]);
    if (decay) v *= expf(log_lam * (float)(127 - (n & 127)));
    t[rr][cc] = v;
  }
  __syncthreads();
  for (int rr = rr0; rr < 32; rr += 8)
    out[((long)bh * 128 + d0 + rr) * 2048 + n0 + cc] = f2bf(t[cc][rr]);
}

// ---------------- decay scan over chunks: S_c = lamC*S_{c-1} + U_{c-1}, S_0 = 0 ----------------
__global__ void scan_state(const u16* __restrict__ U, u16* __restrict__ S_all) {
  int blk = blockIdx.x; // 256 blocks: [bh:32][slice:8]
  int bh = blk >> 3, sl = blk & 7, h = bh & 15;
  float log_lam = -exp2f(-0.5f * (float)(h + 1));
  float lamC = expf(log_lam * 128.f);
  long off = (long)bh * 16 * 16384 + sl * 2048 + threadIdx.x * 8;
  float s[8];
#pragma unroll
  for (int j = 0; j < 8; j++) s[j] = 0.f;
  for (int c = 0; c < 16; c++) {
    long idx = off + (long)c * 16384;
    u16x8 sb;
#pragma unroll
    for (int j = 0; j < 8; j++) sb[j] = f2bf(s[j]);
    *(u16x8*)(S_all + idx) = sb;
    u16x8 ub = *(const u16x8*)(U + idx);
#pragma unroll
    for (int j = 0; j < 8; j++) s[j] = lamC * s[j] + bf2f(ub[j]);
  }
}

// ---------------- fused per-(b,h,c) attention output ----------------
__global__ __launch_bounds__(256, 1) void attn_out(
    const u16* __restrict__ qkv, const u16* __restrict__ vT,
    const u16* __restrict__ S_all, float* __restrict__ o) {
  __shared__ u16 sA[128 * 32], sB[128 * 32], sK[128 * 32];
  __shared__ u16 sS[128 * 136]; // stride 136: breaks 16-way bank conflict
  const int blk = blockIdx.x;
  const int bh = blk >> 4, c = blk & 15;
  const int b = bh >> 4, h = bh & 15;
  const float log_lam = -exp2f(-0.5f * (float)(h + 1));
  const int tid = threadIdx.x, lane = tid & 63, wid = tid >> 6;
  const int wm = (wid & 1) * 64, wn = (wid >> 1) * 64;
  const int fm = lane & 15, fq = lane >> 4, kq = lane >> 4;
  const int ch0 = wid * 2, ch1 = ch0 + 1;
  const int lr = lane >> 2;
  const int ak = (((lane & 3) - ((lane >> 3) & 3)) & 3) * 8;
  const int r0 = ch0 * 16 + lr, r1 = ch1 * 16 + lr;
  const int qs = ((kq + (fm >> 1)) & 3) * 8;
  const int aoff = (wm >> 4) * 512 + fm * 32 + qs;
  const int boff = (wn >> 4) * 512 + fm * 32 + qs;
  const u16* qbase = qkv + (long)(b * 2048 + c * 128) * 6144 + h * 128; // rows t, stride 6144
  const u16* kbase = qbase + 2048;                                     // rows s
  const u16* Sbase = S_all + ((long)bh * 16 + c) * 16384;              // [e][d], stride 128
  const u16* vbase = vT + (long)bh * 262144 + (long)c * 128;           // rows e, stride 2048

  f32x4 acc[4][4] = {}; // o_inter, then O total
  f32x4 sc[4][4] = {};  // scores
  // Phase 1+2: o_inter = Q @ S_c   and   scores = Q @ K^T (shared Q staging)
  for (int kb = 0; kb < 128; kb += 32) {
    async16(qbase + (long)r0 * 6144 + kb + ak, sA + ch0 * 512);
    async16(qbase + (long)r1 * 6144 + kb + ak, sA + ch1 * 512);
    async16(Sbase + r0 * 128 + kb + ak, sB + ch0 * 512);
    async16(Sbase + r1 * 128 + kb + ak, sB + ch1 * 512);
    async16(kbase + (long)r0 * 6144 + kb + ak, sK + ch0 * 512);
    async16(kbase + (long)r1 * 6144 + kb + ak, sK + ch1 * 512);
    __syncthreads();
    bf16x8 aq[4], bs[4], bk[4];
#pragma unroll
    for (int i = 0; i < 4; i++) {
      aq[i] = *(const bf16x8*)&sA[aoff + i * 512];
      bs[i] = *(const bf16x8*)&sB[boff + i * 512];
      bk[i] = *(const bf16x8*)&sK[boff + i * 512];
    }
#pragma unroll
    for (int mt = 0; mt < 4; mt++)
#pragma unroll
      for (int nt = 0; nt < 4; nt++) {
        acc[mt][nt] = __builtin_amdgcn_mfma_f32_16x16x32_bf16(aq[mt], bs[nt], acc[mt][nt], 0, 0, 0);
        sc[mt][nt] = __builtin_amdgcn_mfma_f32_16x16x32_bf16(aq[mt], bk[nt], sc[mt][nt], 0, 0, 0);
      }
    __syncthreads();
  }
  // scale o_inter rows by decay_q(t) = exp(log_lam*(t+1))
#pragma unroll
  for (int mt = 0; mt < 4; mt++)
#pragma unroll
    for (int r = 0; r < 4; r++) {
      int t = wm + mt * 16 + fq * 4 + r;
      float d = expf(log_lam * (float)(t + 1));
#pragma unroll
      for (int nt = 0; nt < 4; nt++) acc[mt][nt][r] *= d;
    }
  // mask+decay scores, write bf16 to sS[t][s]
#pragma unroll
  for (int mt = 0; mt < 4; mt++)
#pragma unroll
    for (int nt = 0; nt < 4; nt++)
#pragma unroll
      for (int r = 0; r < 4; r++) {
        int t = wm + mt * 16 + fq * 4 + r;
        int s = wn + nt * 16 + fm;
        float v = sc[mt][nt][r];
        v = (t >= s) ? v * expf(log_lam * (float)(t - s)) : 0.f;
        sS[t * 136 + s] = f2bf(v);
      }
  __syncthreads();
  // Phase 3: O += scores @ V   (A from sS, B staged from vT)
  for (int kb = 0; kb < 128; kb += 32) {
    async16(vbase + r0 * 2048 + kb + ak, sB + ch0 * 512);
    async16(vbase + r1 * 2048 + kb + ak, sB + ch1 * 512);
    __syncthreads();
    bf16x8 as[4], bv[4];
#pragma unroll
    for (int i = 0; i < 4; i++) {
      as[i] = *(const bf16x8*)&sS[(wm + i * 16 + fm) * 136 + kb + kq * 8];
      bv[i] = *(const bf16x8*)&sB[boff + i * 512];
    }
#pragma unroll
    for (int mt = 0; mt < 4; mt++)
#pragma unroll
      for (int nt = 0; nt < 4; nt++)
        acc[mt][nt] = __builtin_amdgcn_mfma_f32_16x16x32_bf16(as[mt], bv[nt], acc[mt][nt], 0, 0, 0);
    __syncthreads();
  }
  // write O fp32 [b*2048+c*128+t][h*128+e]
  long orow0 = (long)(b * 2048 + c * 128);
#pragma unroll
  for (int mt = 0; mt < 4; mt++)
#pragma unroll
    for (int nt = 0; nt < 4; nt++)
#pragma unroll
      for (int r = 0; r < 4; r++) {
        int t = wm + mt * 16 + fq * 4 + r;
        int e = wn + nt * 16 + fm;
        o[(orow0 + t) * 2048 + h * 128 + e] = acc[mt][nt][r];
      }
}

// ---------------- gated per-head RMSNorm -> bf16 ----------------
__global__ void gated_norm(const float* __restrict__ o, const u16* __restrict__ gate,
                           const float* __restrict__ w, u16* __restrict__ out) {
  int gidx = blockIdx.x * 4 + (threadIdx.x >> 6); // token*16 + h
  int lane = threadIdx.x & 63;
  int h = gidx & 15;
  long base = (long)(gidx >> 4) * 2048 + h * 128;
  float x0 = o[base + lane], x1 = o[base + 64 + lane];
  float g0 = bf2f(gate[base + lane]), g1 = bf2f(gate[base + 64 + lane]);
  x0 *= 1.f / (1.f + expf(-g0));
  x1 *= 1.f / (1.f + expf(-g1));
  float ss = x0 * x0 + x1 * x1;
#pragma unroll
  for (int off = 32; off; off >>= 1) ss += __shfl_xor(ss, off);
  float r = rsqrtf(ss * (1.f / 128.f) + 1e-6f);
  out[base + lane] = f2bf(x0 * r * w[h * 128 + lane]);
  out[base + 64 + lane] = f2bf(x1 * r * w[h * 128 + 64 + lane]);
}

// ---------------- host ----------------
extern "C" void kernel_launch(void* const* d_in, const int* in_sizes, int n_in,
                              void* d_out, int out_size, void* d_ws, size_t ws_size,
                              hipStream_t stream) {
  (void)in_sizes; (void)n_in; (void)out_size; (void)ws_size;
  const float* x   = (const float*)d_in[0];
  const float* Wq  = (const float*)d_in[1];
  const float* Wk  = (const float*)d_in[2];
  const float* Wv  = (const float*)d_in[3];
  const float* Wo  = (const float*)d_in[4];
  const float* Wg1 = (const float*)d_in[5];
  const float* Wg2 = (const float*)d_in[6];
  const float* nw  = (const float*)d_in[7];
  float* out = (float*)d_out;

  char* ws = (char*)d_ws;
  size_t off = 0;
  auto alloc = [&](size_t bytes) -> void* {
    void* p = ws + off;
    off += (bytes + 255) & ~(size_t)255;
    return p;
  };
  u16* xb    = (u16*)alloc(4096UL * 2048 * 2);
  u16* wtqkv = (u16*)alloc(6144UL * 2048 * 2);
  u16* wot   = (u16*)alloc(2048UL * 2048 * 2);
  u16* wg1t  = (u16*)alloc(128UL * 2048 * 2);
  u16* wg2t  = (u16*)alloc(2048UL * 128 * 2);
  u16* qkv   = (u16*)alloc(4096UL * 6144 * 2);
  u16* g1    = (u16*)alloc(4096UL * 128 * 2);
  u16* gate  = (u16*)alloc(4096UL * 2048 * 2); // also aliased as fp32 split-K partials
  u16* kdT   = (u16*)alloc(32UL * 128 * 2048 * 2);
  u16* vT    = (u16*)alloc(32UL * 128 * 2048 * 2);
  u16* Ubuf  = (u16*)alloc(512UL * 16384 * 2);
  u16* S_all = (u16*)alloc(512UL * 16384 * 2);
  float* ob  = (float*)alloc(4096UL * 2048 * 4);
  u16* nrm   = (u16*)alloc(4096UL * 2048 * 2);
  float* g1p = (float*)gate; // 8 x 4096 x 128 fp32 = 16.8 MB, exactly gate's size

  // 1. bf16 conversions / weight transposes
  convert_f32_bf16<<<dim3(8192), dim3(256), 0, stream>>>(x, xb, 8388608L);
  transpose_all<<<dim3(16896), dim3(256), 0, stream>>>(Wq, Wk, Wv, Wo, Wg1, Wg2,
                                                       wtqkv, wot, wg1t, wg2t);
  // 2. projections
  gemm_bt<u16><<<dim3(48, 32, 1), dim3(256), 0, stream>>>(xb, wtqkv, qkv,
      4096, 6144, 2048, 2048, 2048, 6144, 1, 0, 0, 0, 0, 0, 0);
  // gate GEMM1 with split-K=8 (grid 256 blocks instead of 32)
  gemm_bt<float><<<dim3(1, 32, 8), dim3(256), 0, stream>>>(xb, wg1t, g1p,
      4096, 128, 256, 2048, 2048, 128, 1, 256L, 0, 256L, 0, 524288L, 0);
  silu_rotate<<<dim3(16384), dim3(256), 0, stream>>>(qkv);
  reduce_g1<<<dim3(512), dim3(256), 0, stream>>>(g1p, g1);
  gemm_bt<u16><<<dim3(16, 32, 1), dim3(256), 0, stream>>>(g1, wg2t, gate,
      4096, 2048, 128, 128, 128, 2048, 1, 0, 0, 0, 0, 0, 0);
  // 3. attention
  transpose_kv<<<dim3(64, 4, 64), dim3(256), 0, stream>>>(qkv, kdT, vT);
  gemm_bt<u16><<<dim3(1, 1, 512), dim3(256), 0, stream>>>(vT, kdT, Ubuf,
      128, 128, 128, 2048, 2048, 128,
      16, 262144L, 128L, 262144L, 128L, 262144L, 16384L);
  scan_state<<<dim3(256), dim3(256), 0, stream>>>(Ubuf, S_all);
  attn_out<<<dim3(512), dim3(256), 0, stream>>>(qkv, vT, S_all, ob);
  // 4. gated group-RMSNorm + output projection
  gated_norm<<<dim3(16384), dim3(256), 0, stream>>>(ob, gate, nw, nrm);
  gemm_bt<float><<<dim3(16, 32, 1), dim3(256), 0, stream>>>(nrm, wot, out,
      4096, 2048, 2048, 2048, 2048, 2048, 1, 0, 0, 0, 0, 0, 0);
}

// Round 4
// 424.465 us; speedup vs baseline: 1.2848x; 1.0585x over previous
//
#include <hip/hip_runtime.h>

// LinearAttention forward on gfx950.
// R4: Wg1 folded into QKV GEMM (N=6272); silu+rotate fused into QKV epilogue
// via permuted q/k weight columns (pair (j,j+64) -> adjacent nt in same lane);
// gated RMSNorm fused into attn_out (block holds full head tile); 16-wide
// N-supertile swizzle in gemm_bt for L2 locality. 9 dispatches.

#define DEV __device__ __forceinline__
typedef unsigned short u16;
typedef __bf16 bf16x8 __attribute__((ext_vector_type(8)));
typedef float f32x4 __attribute__((ext_vector_type(4)));
typedef u16 u16x8 __attribute__((ext_vector_type(8)));

DEV u16 f2bf(float f) {
  unsigned u = __builtin_bit_cast(unsigned, f);
  u += 0x7fffu + ((u >> 16) & 1u);
  return (u16)(u >> 16);
}
DEV float bf2f(u16 h) {
  unsigned u = ((unsigned)h) << 16;
  return __builtin_bit_cast(float, u);
}
DEV void async16(const u16* g, u16* l) {
  __builtin_amdgcn_global_load_lds(
      (const __attribute__((address_space(1))) unsigned int*)g,
      (__attribute__((address_space(3))) unsigned int*)l, 16, 0, 0);
}

// ---------------- x -> bf16 ----------------
__global__ void convert_f32_bf16(const float* __restrict__ in, u16* __restrict__ out, long n) {
  long i = ((long)blockIdx.x * blockDim.x + threadIdx.x) * 4;
  if (i >= n) return;
  float4 v = *(const float4*)(in + i);
  ushort4 p;
  p.x = f2bf(v.x); p.y = f2bf(v.y); p.z = f2bf(v.z); p.w = f2bf(v.w);
  *(ushort4*)(out + i) = p;
}

// all weight transposes in one launch. fp32 [K][N] -> bf16 [N][K].
// Wq/Wk columns are PERMUTED within each head so the rotation pair (j, j+64)
// lands at adjacent nt tiles of one lane in the GEMM epilogue:
//   n' = h*128 + (jj&15) + 32*(jj>>4) + 16*hi   (j = jj + 64*hi)
__global__ void transpose_all(const float* __restrict__ Wq, const float* __restrict__ Wk,
                              const float* __restrict__ Wv, const float* __restrict__ Wo,
                              const float* __restrict__ Wg1, const float* __restrict__ Wg2,
                              u16* __restrict__ wtqkvg, u16* __restrict__ wot,
                              u16* __restrict__ wg2t) {
  __shared__ float t[32][33];
  int id = blockIdx.x;
  const float* in; u16* out; int K, N, bx, by;
  bool perm = false;
  if (id < 12288) {
    int w = id >> 12, tt = id & 4095;
    in = (w == 0) ? Wq : (w == 1) ? Wk : Wv;
    out = wtqkvg + (long)w * 2048 * 2048;
    K = 2048; N = 2048; bx = tt & 63; by = tt >> 6;
    perm = (w < 2);
  } else if (id < 16384) {
    int tt = id - 12288;
    in = Wo; out = wot; K = 2048; N = 2048; bx = tt & 63; by = tt >> 6;
  } else if (id < 16640) {
    int tt = id - 16384;
    in = Wg1; out = wtqkvg + 6144L * 2048; K = 2048; N = 128; bx = tt & 3; by = tt >> 2;
  } else {
    int tt = id - 16640;
    in = Wg2; out = wg2t; K = 128; N = 2048; bx = tt & 63; by = tt >> 6;
  }
  int c = threadIdx.x & 31, r0 = threadIdx.x >> 5;
  for (int r = r0; r < 32; r += 8)
    t[r][c] = in[(long)(by * 32 + r) * N + bx * 32 + c];
  __syncthreads();
  for (int r = r0; r < 32; r += 8) {
    int n = bx * 32 + r, nr = n;
    if (perm) {
      int h = n >> 7, j = n & 127, jj = j & 63, hi = j >> 6;
      nr = h * 128 + (jj & 15) + 32 * (jj >> 4) + 16 * hi;
    }
    out[(long)nr * K + by * 32 + c] = f2bf(t[c][r]);
  }
}

// ---------------- GEMM: C[M][N] = A[M][K] @ B^T, B stored [N][K], bf16 in ----------------
// Staging: lane 4r+i fetches row r, 16B piece q=(i-(r>>1))&3 (quad-coalesced,
// fragment reads 2-way max bank aliasing). 16-wide N-supertile swizzle.
// rot=1: cols<4096 get silu+LRPE-rotate epilogue (permuted weight cols).
template <typename OutT>
__global__ __launch_bounds__(256, 2) void gemm_bt(
    const u16* __restrict__ A, const u16* __restrict__ B, OutT* __restrict__ C,
    int M, int N, int K, int lda, int ldb, int ldc, int rot,
    int nc, long sA1, long sA2, long sB1, long sB2, long sC1, long sC2) {
  __shared__ u16 sA[128 * 32], sB[128 * 32];
  {
    int z = blockIdx.z, z1 = z / nc, z2 = z % nc;
    A += z1 * sA1 + z2 * sA2;
    B += z1 * sB1 + z2 * sB2;
    C += z1 * sC1 + z2 * sC2;
  }
  int bxs, bys;
  {
    int lin = blockIdx.x + gridDim.x * blockIdx.y;
    int per = 16 * gridDim.y;
    int g = lin / per, r = lin % per;
    int base = g * 16;
    int w = min(16, (int)gridDim.x - base);
    bxs = base + r % w; bys = r / w;
  }
  const int tid = threadIdx.x, lane = tid & 63, wid = tid >> 6;
  const int bm = bys * 128, bn = bxs * 128;
  const int ch0 = wid * 2, ch1 = ch0 + 1;
  const int lr = lane >> 2;                                  // local row 0..15
  const int ak = (((lane & 3) - ((lane >> 3) & 3)) & 3) * 8; // rotated k-piece
  const int ar0 = ch0 * 16 + lr, ar1 = ch1 * 16 + lr;
  const u16* gA0 = A + (long)(bm + ar0) * lda + ak;
  const u16* gA1 = A + (long)(bm + ar1) * lda + ak;
  const u16* gB0 = B + (long)(bn + ar0) * ldb + ak;
  const u16* gB1 = B + (long)(bn + ar1) * ldb + ak;
  u16* lA0 = sA + ch0 * 512; u16* lA1 = sA + ch1 * 512;
  u16* lB0 = sB + ch0 * 512; u16* lB1 = sB + ch1 * 512;
  const int wm = (wid & 1) * 64, wn = (wid >> 1) * 64;
  const int fm = lane & 15, kq = lane >> 4;
  const int qs = ((kq + (fm >> 1)) & 3) * 8;
  const int aoff = (wm >> 4) * 512 + fm * 32 + qs;
  const int boff = (wn >> 4) * 512 + fm * 32 + qs;
  f32x4 acc[4][4] = {};
  for (int kb = 0; kb < K; kb += 32) {
    async16(gA0, lA0); async16(gA1, lA1);
    async16(gB0, lB0); async16(gB1, lB1);
    gA0 += 32; gA1 += 32; gB0 += 32; gB1 += 32;
    __syncthreads();
    bf16x8 af[4], bfr[4];
#pragma unroll
    for (int i = 0; i < 4; i++) af[i] = *(const bf16x8*)&sA[aoff + i * 512];
#pragma unroll
    for (int i = 0; i < 4; i++) bfr[i] = *(const bf16x8*)&sB[boff + i * 512];
#pragma unroll
    for (int mt = 0; mt < 4; mt++)
#pragma unroll
      for (int nt = 0; nt < 4; nt++)
        acc[mt][nt] = __builtin_amdgcn_mfma_f32_16x16x32_bf16(af[mt], bfr[nt], acc[mt][nt], 0, 0, 0);
    __syncthreads();
  }
  const int cr = (lane >> 4) * 4;
  if constexpr (sizeof(OutT) == 2) {
    if (rot && bn < 4096) {
      // silu + rotate epilogue; lane holds permuted cols, stores true cols.
#pragma unroll
      for (int mt = 0; mt < 4; mt++)
#pragma unroll
        for (int r = 0; r < 4; r++) {
          long row = bm + wm + mt * 16 + cr + r;
          float tf = (float)(int)(row & 2047);
#pragma unroll
          for (int np = 0; np < 4; np += 2) {
            float x1 = acc[mt][np][r], x2 = acc[mt][np + 1][r];
            x1 = x1 / (1.f + __expf(-x1));
            x2 = x2 / (1.f + __expf(-x2));
            int jj = fm + 16 * ((wn >> 5) + (np >> 1));
            float th = exp2f(-13.287712379549449f * (float)jj * (1.f / 64.f));
            float sn, cs;
            sincosf(tf * th, &sn, &cs);
            C[row * ldc + bn + jj]      = f2bf(x1 * cs - x2 * sn);
            C[row * ldc + bn + 64 + jj] = f2bf(x1 * sn + x2 * cs);
          }
        }
      return;
    }
  }
#pragma unroll
  for (int mt = 0; mt < 4; mt++)
#pragma unroll
    for (int nt = 0; nt < 4; nt++)
#pragma unroll
      for (int r = 0; r < 4; r++) {
        long row = bm + wm + mt * 16 + cr + r;
        long col = bn + wn + nt * 16 + fm;
        float v = acc[mt][nt][r];
        if constexpr (sizeof(OutT) == 2) C[row * ldc + col] = f2bf(v);
        else                             C[row * ldc + col] = v;
      }
}

// ---------------- per-(b,h) head transpose: [n][dd] -> [dd][n], k gets decay fold ----------------
__global__ void transpose_kv(const u16* __restrict__ qkv, u16* __restrict__ kdT,
                             u16* __restrict__ vT) {
  __shared__ float t[32][33];
  int z = blockIdx.z, which = z >> 5, bh = z & 31;
  int b = bh >> 4, h = bh & 15;
  u16* out = which ? vT : kdT;
  int slab = which ? 2 : 1, decay = which ? 0 : 1;
  int n0 = blockIdx.x * 32, d0 = blockIdx.y * 32;
  int cc = threadIdx.x & 31, rr0 = threadIdx.x >> 5;
  float log_lam = -exp2f(-0.5f * (float)(h + 1));
  for (int rr = rr0; rr < 32; rr += 8) {
    int n = n0 + rr;
    float v = bf2f(qkv[(long)(b * 2048 + n) * 6272 + slab * 2048 + h * 128 + d0 + cc]);
    if (decay) v *= expf(log_lam * (float)(127 - (n & 127)));
    t[rr][cc] = v;
  }
  __syncthreads();
  for (int rr = rr0; rr < 32; rr += 8)
    out[((long)bh * 128 + d0 + rr) * 2048 + n0 + cc] = f2bf(t[cc][rr]);
}

// ---------------- decay scan over chunks: S_c = lamC*S_{c-1} + U_{c-1}, S_0 = 0 ----------------
__global__ void scan_state(const u16* __restrict__ U, u16* __restrict__ S_all) {
  int blk = blockIdx.x; // 256 blocks: [bh:32][slice:8]
  int bh = blk >> 3, sl = blk & 7, h = bh & 15;
  float log_lam = -exp2f(-0.5f * (float)(h + 1));
  float lamC = expf(log_lam * 128.f);
  long off = (long)bh * 16 * 16384 + sl * 2048 + threadIdx.x * 8;
  float s[8];
#pragma unroll
  for (int j = 0; j < 8; j++) s[j] = 0.f;
  for (int c = 0; c < 16; c++) {
    long idx = off + (long)c * 16384;
    u16x8 sb;
#pragma unroll
    for (int j = 0; j < 8; j++) sb[j] = f2bf(s[j]);
    *(u16x8*)(S_all + idx) = sb;
    u16x8 ub = *(const u16x8*)(U + idx);
#pragma unroll
    for (int j = 0; j < 8; j++) s[j] = lamC * s[j] + bf2f(ub[j]);
  }
}

// ---------------- fused per-(b,h,c) attention output + gated RMSNorm ----------------
__global__ __launch_bounds__(256, 1) void attn_out(
    const u16* __restrict__ qkv, const u16* __restrict__ vT,
    const u16* __restrict__ S_all, const u16* __restrict__ gate,
    const float* __restrict__ nw, u16* __restrict__ nrm) {
  __shared__ u16 sA[128 * 32], sB[128 * 32], sK[128 * 32];
  __shared__ u16 sS[128 * 136]; // stride 136: breaks 16-way bank conflict
  __shared__ float sNorm[2][128];
  const int blk = blockIdx.x;
  const int bh = blk >> 4, c = blk & 15;
  const int b = bh >> 4, h = bh & 15;
  const float log_lam = -exp2f(-0.5f * (float)(h + 1));
  const int tid = threadIdx.x, lane = tid & 63, wid = tid >> 6;
  const int wm = (wid & 1) * 64, wn = (wid >> 1) * 64;
  const int fm = lane & 15, fq = lane >> 4, kq = lane >> 4;
  const int lr = lane >> 2;
  const int ak = (((lane & 3) - ((lane >> 3) & 3)) & 3) * 8;
  const int ch0 = wid * 2, ch1 = ch0 + 1;
  const int r0 = ch0 * 16 + lr, r1 = ch1 * 16 + lr;
  const int qs = ((kq + (fm >> 1)) & 3) * 8;
  const int aoff = (wm >> 4) * 512 + fm * 32 + qs;
  const int boff = (wn >> 4) * 512 + fm * 32 + qs;
  const u16* qbase = qkv + (long)(b * 2048 + c * 128) * 6272 + h * 128; // rows t, stride 6272
  const u16* kbase = qbase + 2048;                                     // rows s
  const u16* Sbase = S_all + ((long)bh * 16 + c) * 16384;              // [e][d], stride 128
  const u16* vbase = vT + (long)bh * 262144 + (long)c * 128;           // rows e, stride 2048

  f32x4 acc[4][4] = {}; // o_inter, then O total
  f32x4 sc[4][4] = {};  // scores
  // Phase 1+2: o_inter = Q @ S_c   and   scores = Q @ K^T (shared Q staging)
  for (int kb = 0; kb < 128; kb += 32) {
    async16(qbase + (long)r0 * 6272 + kb + ak, sA + ch0 * 512);
    async16(qbase + (long)r1 * 6272 + kb + ak, sA + ch1 * 512);
    async16(Sbase + r0 * 128 + kb + ak, sB + ch0 * 512);
    async16(Sbase + r1 * 128 + kb + ak, sB + ch1 * 512);
    async16(kbase + (long)r0 * 6272 + kb + ak, sK + ch0 * 512);
    async16(kbase + (long)r1 * 6272 + kb + ak, sK + ch1 * 512);
    __syncthreads();
    bf16x8 aq[4], bs[4], bk[4];
#pragma unroll
    for (int i = 0; i < 4; i++) {
      aq[i] = *(const bf16x8*)&sA[aoff + i * 512];
      bs[i] = *(const bf16x8*)&sB[boff + i * 512];
      bk[i] = *(const bf16x8*)&sK[boff + i * 512];
    }
#pragma unroll
    for (int mt = 0; mt < 4; mt++)
#pragma unroll
      for (int nt = 0; nt < 4; nt++) {
        acc[mt][nt] = __builtin_amdgcn_mfma_f32_16x16x32_bf16(aq[mt], bs[nt], acc[mt][nt], 0, 0, 0);
        sc[mt][nt] = __builtin_amdgcn_mfma_f32_16x16x32_bf16(aq[mt], bk[nt], sc[mt][nt], 0, 0, 0);
      }
    __syncthreads();
  }
  // scale o_inter rows by decay_q(t) = exp(log_lam*(t+1))
#pragma unroll
  for (int mt = 0; mt < 4; mt++)
#pragma unroll
    for (int r = 0; r < 4; r++) {
      int t = wm + mt * 16 + fq * 4 + r;
      float d = expf(log_lam * (float)(t + 1));
#pragma unroll
      for (int nt = 0; nt < 4; nt++) acc[mt][nt][r] *= d;
    }
  // mask+decay scores, write bf16 to sS[t][s]
#pragma unroll
  for (int mt = 0; mt < 4; mt++)
#pragma unroll
    for (int nt = 0; nt < 4; nt++)
#pragma unroll
      for (int r = 0; r < 4; r++) {
        int t = wm + mt * 16 + fq * 4 + r;
        int s = wn + nt * 16 + fm;
        float v = sc[mt][nt][r];
        v = (t >= s) ? v * expf(log_lam * (float)(t - s)) : 0.f;
        sS[t * 136 + s] = f2bf(v);
      }
  __syncthreads();
  // Phase 3: O += scores @ V   (A from sS, B staged from vT)
  for (int kb = 0; kb < 128; kb += 32) {
    async16(vbase + r0 * 2048 + kb + ak, sB + ch0 * 512);
    async16(vbase + r1 * 2048 + kb + ak, sB + ch1 * 512);
    __syncthreads();
    bf16x8 as[4], bv[4];
#pragma unroll
    for (int i = 0; i < 4; i++) {
      as[i] = *(const bf16x8*)&sS[(wm + i * 16 + fm) * 136 + kb + kq * 8];
      bv[i] = *(const bf16x8*)&sB[boff + i * 512];
    }
#pragma unroll
    for (int mt = 0; mt < 4; mt++)
#pragma unroll
      for (int nt = 0; nt < 4; nt++)
        acc[mt][nt] = __builtin_amdgcn_mfma_f32_16x16x32_bf16(as[mt], bv[nt], acc[mt][nt], 0, 0, 0);
    __syncthreads();
  }
  // ---- fused gated group-RMSNorm: x = O*sigmoid(gate); per-row mean over e ----
  const u16* gbase = gate + (long)(b * 2048 + c * 128) * 2048 + h * 128;
  float nwv[4];
#pragma unroll
  for (int nt = 0; nt < 4; nt++) nwv[nt] = nw[h * 128 + wn + nt * 16 + fm];
  float part[4][4];
#pragma unroll
  for (int mt = 0; mt < 4; mt++)
#pragma unroll
    for (int r = 0; r < 4; r++) {
      int t = wm + mt * 16 + fq * 4 + r;
      float p = 0.f;
#pragma unroll
      for (int nt = 0; nt < 4; nt++) {
        int e = wn + nt * 16 + fm;
        float g = bf2f(gbase[(long)t * 2048 + e]);
        float x = acc[mt][nt][r] / (1.f + __expf(-g));
        acc[mt][nt][r] = x;
        p += x * x;
      }
      part[mt][r] = p;
    }
#pragma unroll
  for (int o = 1; o < 16; o <<= 1)
#pragma unroll
    for (int mt = 0; mt < 4; mt++)
#pragma unroll
      for (int r = 0; r < 4; r++) part[mt][r] += __shfl_xor(part[mt][r], o);
  if (fm == 0) {
#pragma unroll
    for (int mt = 0; mt < 4; mt++)
#pragma unroll
      for (int r = 0; r < 4; r++)
        sNorm[wid >> 1][wm + mt * 16 + fq * 4 + r] = part[mt][r];
  }
  __syncthreads();
  long orow0 = (long)(b * 2048 + c * 128);
#pragma unroll
  for (int mt = 0; mt < 4; mt++)
#pragma unroll
    for (int r = 0; r < 4; r++) {
      int t = wm + mt * 16 + fq * 4 + r;
      float ms = (sNorm[0][t] + sNorm[1][t]) * (1.f / 128.f);
      float rs = rsqrtf(ms + 1e-6f);
#pragma unroll
      for (int nt = 0; nt < 4; nt++) {
        int e = wn + nt * 16 + fm;
        nrm[(orow0 + t) * 2048 + h * 128 + e] = f2bf(acc[mt][nt][r] * rs * nwv[nt]);
      }
    }
}

// ---------------- host ----------------
extern "C" void kernel_launch(void* const* d_in, const int* in_sizes, int n_in,
                              void* d_out, int out_size, void* d_ws, size_t ws_size,
                              hipStream_t stream) {
  (void)in_sizes; (void)n_in; (void)out_size; (void)ws_size;
  const float* x   = (const float*)d_in[0];
  const float* Wq  = (const float*)d_in[1];
  const float* Wk  = (const float*)d_in[2];
  const float* Wv  = (const float*)d_in[3];
  const float* Wo  = (const float*)d_in[4];
  const float* Wg1 = (const float*)d_in[5];
  const float* Wg2 = (const float*)d_in[6];
  const float* nw  = (const float*)d_in[7];
  float* out = (float*)d_out;

  char* ws = (char*)d_ws;
  size_t off = 0;
  auto alloc = [&](size_t bytes) -> void* {
    void* p = ws + off;
    off += (bytes + 255) & ~(size_t)255;
    return p;
  };
  u16* xb    = (u16*)alloc(4096UL * 2048 * 2);
  u16* wtqkv = (u16*)alloc(6272UL * 2048 * 2); // [Wq^T perm | Wk^T perm | Wv^T | Wg1^T]
  u16* wot   = (u16*)alloc(2048UL * 2048 * 2);
  u16* wg2t  = (u16*)alloc(2048UL * 128 * 2);
  u16* qkvg  = (u16*)alloc(4096UL * 6272 * 2); // q(rot) | k(rot) | v | g1
  u16* gate  = (u16*)alloc(4096UL * 2048 * 2);
  u16* kdT   = (u16*)alloc(32UL * 128 * 2048 * 2);
  u16* vT    = (u16*)alloc(32UL * 128 * 2048 * 2);
  u16* Ubuf  = (u16*)alloc(512UL * 16384 * 2);
  u16* S_all = (u16*)alloc(512UL * 16384 * 2);
  u16* nrm   = (u16*)alloc(4096UL * 2048 * 2);

  // 1. bf16 conversions / weight transposes
  convert_f32_bf16<<<dim3(8192), dim3(256), 0, stream>>>(x, xb, 8388608L);
  transpose_all<<<dim3(16896), dim3(256), 0, stream>>>(Wq, Wk, Wv, Wo, Wg1, Wg2,
                                                       wtqkv, wot, wg2t);
  // 2. QKV+g1 projection with fused silu+rotate epilogue on q,k cols
  gemm_bt<u16><<<dim3(49, 32, 1), dim3(256), 0, stream>>>(xb, wtqkv, qkvg,
      4096, 6272, 2048, 2048, 2048, 6272, 1, 1, 0, 0, 0, 0, 0, 0);
  // gate = g1 @ Wg2^T
  gemm_bt<u16><<<dim3(16, 32, 1), dim3(256), 0, stream>>>(qkvg + 6144, wg2t, gate,
      4096, 2048, 128, 6272, 128, 2048, 0, 1, 0, 0, 0, 0, 0, 0);
  // 3. attention
  transpose_kv<<<dim3(64, 4, 64), dim3(256), 0, stream>>>(qkvg, kdT, vT);
  gemm_bt<u16><<<dim3(1, 1, 512), dim3(256), 0, stream>>>(vT, kdT, Ubuf,
      128, 128, 128, 2048, 2048, 128, 0,
      16, 262144L, 128L, 262144L, 128L, 262144L, 16384L);
  scan_state<<<dim3(256), dim3(256), 0, stream>>>(Ubuf, S_all);
  attn_out<<<dim3(512), dim3(256), 0, stream>>>(qkvg, vT, S_all, gate, nw, nrm);
  // 4. output projection
  gemm_bt<float><<<dim3(16, 32, 1), dim3(256), 0, stream>>>(nrm, wot, out,
      4096, 2048, 2048, 2048, 2048, 2048, 0, 1, 0, 0, 0, 0, 0, 0);
}